// Round 1
// baseline (678.630 us; speedup 1.0000x reference)
//
#include <hip/hip_runtime.h>

#define DIM_IN 256
#define DIM_H 64
#define SEQ_LEN 512

typedef _Float16 h2_t __attribute__((ext_vector_type(2)));

#if defined(__HIP_DEVICE_COMPILE__) && __has_builtin(__builtin_amdgcn_fdot2)
__device__ inline float dot2(h2_t a, h2_t b, float c) {
    return __builtin_amdgcn_fdot2(a, b, c, false);
}
#else
__device__ inline float dot2(h2_t a, h2_t b, float c) {
    return c + (float)a[0] * (float)b[0] + (float)a[1] * (float)b[1];
}
#endif

// One block per batch row. 256 threads: thread = (j, kc), j = tid>>2 owns output
// column j, kc = tid&3 splits the K dimension 4 ways (x: 64 each, h: 16 each).
// Reduction over kc via __shfl_xor(1),(2) — kc lives in lane bits [1:0].
// Wx held in registers as packed fp16 (96 VGPRs), Wh in fp32 (48 VGPRs).
// h carried fp32; x converted to fp16 once per step in LDS.
__global__ __launch_bounds__(256, 1)
void gru_fused(const float* __restrict__ inputs,
               const float* __restrict__ W_input,  const float* __restrict__ b_input,
               const float* __restrict__ W_update, const float* __restrict__ b_update,
               const float* __restrict__ W_reset,  const float* __restrict__ b_reset,
               float* __restrict__ out)
{
    const int b   = blockIdx.x;
    const int tid = threadIdx.x;
    const int j   = tid >> 2;   // hidden unit owned by this thread
    const int kc  = tid & 3;    // K-chunk index

    __shared__ _Float16 xs[2][DIM_IN];  // current/next input row, fp16
    __shared__ float    hs[2][DIM_H];   // hidden state double buffer
    __shared__ float    rs[DIM_H];      // reset gate broadcast

    // ---- load weights into registers (once per block) ----
    h2_t wxu[32], wxr[32], wxi[32];     // x-part columns, packed fp16 pairs
    float whu[16], whr[16], whi[16];    // h-part columns, fp32
    {
        const int k0 = 64 * kc;
#pragma unroll
        for (int m = 0; m < 32; ++m) {
            const int k = k0 + 2 * m;
            h2_t tu, tr, ti;
            tu[0] = (_Float16)W_update[(k    ) * DIM_H + j];
            tu[1] = (_Float16)W_update[(k + 1) * DIM_H + j];
            tr[0] = (_Float16)W_reset [(k    ) * DIM_H + j];
            tr[1] = (_Float16)W_reset [(k + 1) * DIM_H + j];
            ti[0] = (_Float16)W_input [(k    ) * DIM_H + j];
            ti[1] = (_Float16)W_input [(k + 1) * DIM_H + j];
            wxu[m] = tu; wxr[m] = tr; wxi[m] = ti;
        }
#pragma unroll
        for (int m = 0; m < 16; ++m) {
            const int k = DIM_IN + 16 * kc + m;
            whu[m] = W_update[k * DIM_H + j];
            whr[m] = W_reset [k * DIM_H + j];
            whi[m] = W_input [k * DIM_H + j];
        }
    }
    const float bz = b_update[j];
    const float br = b_reset [j];
    const float bi = b_input [j];

    const float* xin  = inputs + (size_t)b * SEQ_LEN * DIM_IN;
    float*       outb = out    + (size_t)b * SEQ_LEN * DIM_H;

    // ---- init: stage x(t=0), zero h ----
    xs[0][tid] = (_Float16)xin[tid];
    if (tid < DIM_H) hs[0][tid] = 0.0f;
    float hprev = 0.0f;   // h_prev[j], replicated on all 4 kc lanes
    __syncthreads();

    for (int t = 0; t < SEQ_LEN; ++t) {
        const int p = t & 1;

        // prefetch next step's input row (latency hidden by this step's compute)
        const int tn = (t + 1 < SEQ_LEN) ? (t + 1) : t;
        const float xnf = xin[tn * DIM_IN + tid];

        // load this thread's x chunk (64 fp16 = 32 half2) and h chunk (16 fp32)
        h2_t x2[32];
        const h2_t* xsp = (const h2_t*)&xs[p][64 * kc];
#pragma unroll
        for (int m = 0; m < 32; ++m) x2[m] = xsp[m];

        float hk[16];
        const float* hsp = &hs[p][16 * kc];
#pragma unroll
        for (int m = 0; m < 16; ++m) hk[m] = hsp[m];

        // partial pre-activations
        float az = 0.0f, ar = 0.0f, ax = 0.0f;
#pragma unroll
        for (int m = 0; m < 32; ++m) {
            az = dot2(x2[m], wxu[m], az);
            ar = dot2(x2[m], wxr[m], ar);
            ax = dot2(x2[m], wxi[m], ax);
        }
#pragma unroll
        for (int m = 0; m < 16; ++m) {
            az += hk[m] * whu[m];
            ar += hk[m] * whr[m];
        }
        // reduce across the 4 kc lanes (bit-identical on all 4 afterwards)
        az += __shfl_xor(az, 1); az += __shfl_xor(az, 2);
        ar += __shfl_xor(ar, 1); ar += __shfl_xor(ar, 2);

        const float z = __fdividef(1.0f, 1.0f + __expf(-(az + bz)));
        const float r = __fdividef(1.0f, 1.0f + __expf(-(ar + br)));

        if (kc == 0) rs[j] = r;
        __syncthreads();

        // candidate: ax += sum_k (h[k]*r[k]) * Wi_h[k][j]
        const float* rsp = &rs[16 * kc];
#pragma unroll
        for (int m = 0; m < 16; ++m) ax += (hk[m] * rsp[m]) * whi[m];
        ax += __shfl_xor(ax, 1); ax += __shfl_xor(ax, 2);

        const float aval = ax + bi;
        const float th = 1.0f - 2.0f * __fdividef(1.0f, 1.0f + __expf(2.0f * aval));
        const float hn = (1.0f - z) * hprev + z * th;
        hprev = hn;

        if (kc == 0) {
            outb[t * DIM_H + j] = hn;
            hs[1 - p][j] = hn;
        }
        xs[1 - p][tid] = (_Float16)xnf;
        __syncthreads();
    }
}

extern "C" void kernel_launch(void* const* d_in, const int* in_sizes, int n_in,
                              void* d_out, int out_size, void* d_ws, size_t ws_size,
                              hipStream_t stream) {
    const float* inputs   = (const float*)d_in[0];
    const float* W_input  = (const float*)d_in[1];
    const float* b_input  = (const float*)d_in[2];
    const float* W_update = (const float*)d_in[3];
    const float* b_update = (const float*)d_in[4];
    const float* W_reset  = (const float*)d_in[5];
    const float* b_reset  = (const float*)d_in[6];
    float* out = (float*)d_out;

    const int batch = in_sizes[0] / (SEQ_LEN * DIM_IN);
    gru_fused<<<batch, 256, 0, stream>>>(inputs, W_input, b_input,
                                         W_update, b_update, W_reset, b_reset, out);
}

// Round 2
// 589.350 us; speedup vs baseline: 1.1515x; 1.1515x over previous
//
#include <hip/hip_runtime.h>

#define DIM_IN 256
#define DIM_H 64
#define SEQ_LEN 512

typedef _Float16 h2_t __attribute__((ext_vector_type(2)));
typedef _Float16 h8_t __attribute__((ext_vector_type(8)));

union H8 { h8_t v; h2_t p[4]; };

__device__ inline float dot2(h2_t a, h2_t b, float c) {
#if __has_builtin(__builtin_amdgcn_fdot2)
    return __builtin_amdgcn_fdot2(a, b, c, false);
#else
    return c + (float)a[0] * (float)b[0] + (float)a[1] * (float)b[1];
#endif
}

__device__ inline float sigmoid_(float x) {
    return __fdividef(1.0f, 1.0f + __expf(-x));
}
__device__ inline float tanh_(float x) {
    return 1.0f - 2.0f * __fdividef(1.0f, 1.0f + __expf(2.0f * x));
}

// ---------------------------------------------------------------------------
// Pass 1: x-projections for all (b,t) rows — embarrassingly parallel GEMM.
//   xi (into tanh, precision-critical) -> d_out as fp32 (recurrence reads it
//   at step t just before overwriting the same slot with h_t).
//   xu, xr (into sigmoids) -> d_ws as fp16 (2 x 16.8 MB; assumes ws >= 34 MB).
// Block: 256 threads = (j, kc) like R1; 64 rows per block; W_x in registers
// amortized over the 64 rows; X tile staged fp16 in LDS (32 KB).
// ---------------------------------------------------------------------------
__global__ __launch_bounds__(256, 1)
void gru_prepass(const float* __restrict__ X,
                 const float* __restrict__ W_input,  const float* __restrict__ b_input,
                 const float* __restrict__ W_update, const float* __restrict__ b_update,
                 const float* __restrict__ W_reset,  const float* __restrict__ b_reset,
                 float* __restrict__ xi_out,
                 _Float16* __restrict__ xu_out, _Float16* __restrict__ xr_out)
{
    const int tid = threadIdx.x;
    const int j  = tid >> 2;   // output column
    const int kc = tid & 3;    // 4-way K split (shfl_xor 1,2 reduces)

    __shared__ __align__(16) h2_t xs2[64 * 128];   // 64 rows x 256 k, fp16

    // x-part weight columns in registers, 64 k per thread, fp16 pairs
    h2_t wu[32], wr[32], wi[32];
    {
        const int k0 = 64 * kc;
#pragma unroll
        for (int m = 0; m < 32; ++m) {
            const int k = k0 + 2 * m;
            h2_t a, b, c;
            a[0] = (_Float16)W_update[(k    ) * DIM_H + j];
            a[1] = (_Float16)W_update[(k + 1) * DIM_H + j];
            b[0] = (_Float16)W_reset [(k    ) * DIM_H + j];
            b[1] = (_Float16)W_reset [(k + 1) * DIM_H + j];
            c[0] = (_Float16)W_input [(k    ) * DIM_H + j];
            c[1] = (_Float16)W_input [(k + 1) * DIM_H + j];
            wu[m] = a; wr[m] = b; wi[m] = c;
        }
    }
    const float bz = b_update[j], br = b_reset[j], bi = b_input[j];

    // stage 64 rows of X (64 KB fp32 -> 32 KB fp16), coalesced float4 loads
    const float4* xblk = (const float4*)(X + (size_t)blockIdx.x * 64 * DIM_IN);
#pragma unroll
    for (int i = 0; i < 16; ++i) {
        const int f = tid + 256 * i;
        const float4 v = xblk[f];
        h2_t a, b;
        a[0] = (_Float16)v.x; a[1] = (_Float16)v.y;
        b[0] = (_Float16)v.z; b[1] = (_Float16)v.w;
        xs2[2 * f] = a; xs2[2 * f + 1] = b;
    }
    __syncthreads();

    const size_t orow = (size_t)blockIdx.x * 64;
    for (int r = 0; r < 64; ++r) {
        const H8* xp = (const H8*)&xs2[r * 128 + kc * 32];
        float au = 0.0f, as = 0.0f, ai = 0.0f;
#pragma unroll
        for (int q = 0; q < 8; ++q) {
            H8 hx; hx.v = xp[q].v;
#pragma unroll
            for (int p = 0; p < 4; ++p) {
                const int m = 4 * q + p;
                au = dot2(hx.p[p], wu[m], au);
                as = dot2(hx.p[p], wr[m], as);
                ai = dot2(hx.p[p], wi[m], ai);
            }
        }
        au += __shfl_xor(au, 1); au += __shfl_xor(au, 2);
        as += __shfl_xor(as, 1); as += __shfl_xor(as, 2);
        ai += __shfl_xor(ai, 1); ai += __shfl_xor(ai, 2);

        const size_t o = (orow + r) * DIM_H + j;
        if (kc == 0)      xi_out[o] = ai + bi;
        else if (kc == 1) xu_out[o] = (_Float16)(au + bz);
        else if (kc == 2) xr_out[o] = (_Float16)(as + br);
    }
}

// ---------------------------------------------------------------------------
// Pass 2: the recurrence. ONE WAVE PER CHAIN: lane j owns hidden unit j,
// does full 64-deep h-dots (fp16 pairs, fp32 accumulate). All cross-lane
// traffic is intra-wave: h and (h*r) round-trip through 128 B of LDS with
// same-address b128 broadcasts; no shuffles, single-wave barriers.
// W_h columns live in 96 VGPRs. xi is read from d_out and overwritten by h.
// ---------------------------------------------------------------------------
__global__ __launch_bounds__(64, 1)
void gru_rec(const _Float16* __restrict__ xu_pre, const _Float16* __restrict__ xr_pre,
             const float* __restrict__ W_input, const float* __restrict__ W_update,
             const float* __restrict__ W_reset,
             float* __restrict__ out /* holds xi fp32 on entry */)
{
    const int b = blockIdx.x;
    const int j = threadIdx.x;

    __shared__ __align__(16) h2_t hh[DIM_H / 2];   // h state, fp16
    __shared__ __align__(16) h2_t ss[DIM_H / 2];   // h*r, fp16

    // h-part weight columns (rows DIM_IN..DIM_IN+63), fp16 pairs in registers
    h2_t wu[32], wr[32], wi[32];
#pragma unroll
    for (int m = 0; m < 32; ++m) {
        const int k = DIM_IN + 2 * m;
        h2_t a, c, d;
        a[0] = (_Float16)W_update[(k    ) * DIM_H + j];
        a[1] = (_Float16)W_update[(k + 1) * DIM_H + j];
        c[0] = (_Float16)W_reset [(k    ) * DIM_H + j];
        c[1] = (_Float16)W_reset [(k + 1) * DIM_H + j];
        d[0] = (_Float16)W_input [(k    ) * DIM_H + j];
        d[1] = (_Float16)W_input [(k + 1) * DIM_H + j];
        wu[m] = a; wr[m] = c; wi[m] = d;
    }

    ((_Float16*)hh)[j] = (_Float16)0.0f;
    float hprev = 0.0f;

    const size_t base = (size_t)b * SEQ_LEN * DIM_H + j;
    float xi_t = out[base];                 // t = 0 (written by prepass)
    float xu_t = (float)xu_pre[base];
    float xr_t = (float)xr_pre[base];
    __syncthreads();

    for (int t = 0; t < SEQ_LEN; ++t) {
        // prefetch t+1 (t=511 re-reads its own xi slot before the store: safe)
        const int tn = (t + 1 < SEQ_LEN) ? (t + 1) : t;
        const size_t on = base + (size_t)tn * DIM_H;
        const float xi_n = out[on];
        const float xu_n = (float)xu_pre[on];
        const float xr_n = (float)xr_pre[on];

        // z / r gates: h broadcast from LDS, 2 interleaved dot chains
        const H8* hp = (const H8*)hh;
        float az = 0.0f, ar = 0.0f;
#pragma unroll
        for (int q = 0; q < 8; ++q) {
            H8 hx; hx.v = hp[q].v;
#pragma unroll
            for (int p = 0; p < 4; ++p) {
                const int m = 4 * q + p;
                az = dot2(hx.p[p], wu[m], az);
                ar = dot2(hx.p[p], wr[m], ar);
            }
        }
        const float z = sigmoid_(xu_t + az);
        const float r = sigmoid_(xr_t + ar);

        ((_Float16*)ss)[j] = (_Float16)(hprev * r);
        __syncthreads();

        // candidate: (h.*r) @ Wi_h
        const H8* sp = (const H8*)ss;
        float ax = 0.0f;
#pragma unroll
        for (int q = 0; q < 8; ++q) {
            H8 sx; sx.v = sp[q].v;
#pragma unroll
            for (int p = 0; p < 4; ++p)
                ax = dot2(sx.p[p], wi[4 * q + p], ax);
        }
        const float th = tanh_(xi_t + ax);
        const float hn = (1.0f - z) * hprev + z * th;

        out[base + (size_t)t * DIM_H] = hn;     // overwrite xi slot with h_t
        ((_Float16*)hh)[j] = (_Float16)hn;
        hprev = hn;
        xi_t = xi_n; xu_t = xu_n; xr_t = xr_n;
        __syncthreads();
    }
}

extern "C" void kernel_launch(void* const* d_in, const int* in_sizes, int n_in,
                              void* d_out, int out_size, void* d_ws, size_t ws_size,
                              hipStream_t stream) {
    const float* inputs   = (const float*)d_in[0];
    const float* W_input  = (const float*)d_in[1];
    const float* b_input  = (const float*)d_in[2];
    const float* W_update = (const float*)d_in[3];
    const float* b_update = (const float*)d_in[4];
    const float* W_reset  = (const float*)d_in[5];
    const float* b_reset  = (const float*)d_in[6];
    float* out = (float*)d_out;

    const int    batch = in_sizes[0] / (SEQ_LEN * DIM_IN);
    const size_t rows  = (size_t)batch * SEQ_LEN;

    // workspace: xu, xr as fp16 — 2 * rows * 64 * 2 B = 33.6 MB at batch=256
    _Float16* xu_w = (_Float16*)d_ws;
    _Float16* xr_w = xu_w + rows * DIM_H;

    gru_prepass<<<(int)(rows / 64), 256, 0, stream>>>(
        inputs, W_input, b_input, W_update, b_update, W_reset, b_reset,
        out, xu_w, xr_w);
    gru_rec<<<batch, 64, 0, stream>>>(xu_w, xr_w, W_input, W_update, W_reset, out);
}

// Round 3
// 582.277 us; speedup vs baseline: 1.1655x; 1.0121x over previous
//
#include <hip/hip_runtime.h>

#define DIM_IN 256
#define DIM_H 64
#define SEQ_LEN 512

typedef _Float16 h2_t __attribute__((ext_vector_type(2)));
typedef _Float16 h8_t __attribute__((ext_vector_type(8)));
union H8 { h8_t v; h2_t p[4]; };

__device__ inline float dot2(h2_t a, h2_t b, float c) {
#if __has_builtin(__builtin_amdgcn_fdot2)
    return __builtin_amdgcn_fdot2(a, b, c, false);
#else
    return c + (float)a[0] * (float)b[0] + (float)a[1] * (float)b[1];
#endif
}
__device__ inline float sigmoid_(float x) { return __fdividef(1.f, 1.f + __expf(-x)); }
__device__ inline float tanh_(float x)    { return 1.f - 2.f * __fdividef(1.f, 1.f + __expf(2.f * x)); }

// Sum over lane groups of 4 (kc lives in lane bits [1:0]) on the VALU pipe
// via DPP quad_perm — replaces __shfl_xor's ds_swizzle (LDS pipe).
__device__ inline float dpp_sum4(float x) {
    int a = __builtin_bit_cast(int, x);
    int b = __builtin_amdgcn_mov_dpp(a, 0xB1, 0xF, 0xF, true);  // quad_perm [1,0,3,2]
    float s = x + __builtin_bit_cast(float, b);
    int c = __builtin_bit_cast(int, s);
    int d = __builtin_amdgcn_mov_dpp(c, 0x4E, 0xF, 0xF, true);  // quad_perm [2,3,0,1]
    return s + __builtin_bit_cast(float, d);
}

// ---------------------------------------------------------------------------
// Pass 1: x-projections (x @ Wx + b) for all rows. 256 threads = (j, kc);
// kc-reduction via DPP (VALU), x staged fp16 in LDS, weights in registers.
// xu, xr always fp16 -> ws. xi: fp16 -> ws (XI16=1) or fp32 -> out (XI16=0).
// ---------------------------------------------------------------------------
template <int XI16>
__global__ __launch_bounds__(256, 1)
void gru_prepass(const float* __restrict__ X,
                 const float* __restrict__ W_input,  const float* __restrict__ b_input,
                 const float* __restrict__ W_update, const float* __restrict__ b_update,
                 const float* __restrict__ W_reset,  const float* __restrict__ b_reset,
                 _Float16* __restrict__ xu_out, _Float16* __restrict__ xr_out,
                 _Float16* __restrict__ xi16_out, float* __restrict__ xi32_out)
{
    const int tid = threadIdx.x;
    const int j   = tid >> 2;
    const int kc  = tid & 3;

    __shared__ __align__(16) h2_t xs2[64 * 128];   // 64 rows x 256 k, fp16

    h2_t wu[32], wr[32], wi[32];
    {
        const int k0 = 64 * kc;
#pragma unroll
        for (int m = 0; m < 32; ++m) {
            const int k = k0 + 2 * m;
            h2_t a, b, c;
            a[0] = (_Float16)W_update[(k    ) * DIM_H + j];
            a[1] = (_Float16)W_update[(k + 1) * DIM_H + j];
            b[0] = (_Float16)W_reset [(k    ) * DIM_H + j];
            b[1] = (_Float16)W_reset [(k + 1) * DIM_H + j];
            c[0] = (_Float16)W_input [(k    ) * DIM_H + j];
            c[1] = (_Float16)W_input [(k + 1) * DIM_H + j];
            wu[m] = a; wr[m] = b; wi[m] = c;
        }
    }
    const float bz = b_update[j], br = b_reset[j], bi = b_input[j];

    const float4* xblk = (const float4*)(X + (size_t)blockIdx.x * 64 * DIM_IN);
#pragma unroll
    for (int i = 0; i < 16; ++i) {
        const int f = tid + 256 * i;
        const float4 v = xblk[f];
        h2_t a, b;
        a[0] = (_Float16)v.x; a[1] = (_Float16)v.y;
        b[0] = (_Float16)v.z; b[1] = (_Float16)v.w;
        xs2[2 * f] = a; xs2[2 * f + 1] = b;
    }
    __syncthreads();

    const size_t orow = (size_t)blockIdx.x * 64;
    for (int r = 0; r < 64; ++r) {
        const H8* xp = (const H8*)&xs2[r * 128 + kc * 32];
        float au = 0.f, as = 0.f, ai = 0.f;
#pragma unroll
        for (int q = 0; q < 8; ++q) {
            H8 hx; hx.v = xp[q].v;
#pragma unroll
            for (int p = 0; p < 4; ++p) {
                const int m = 4 * q + p;
                au = dot2(hx.p[p], wu[m], au);
                as = dot2(hx.p[p], wr[m], as);
                ai = dot2(hx.p[p], wi[m], ai);
            }
        }
        au = dpp_sum4(au); as = dpp_sum4(as); ai = dpp_sum4(ai);

        const size_t o = (orow + r) * DIM_H + j;
        if (kc == 0)      xu_out[o] = (_Float16)(au + bz);
        else if (kc == 1) xr_out[o] = (_Float16)(as + br);
        else if (kc == 2) {
            if (XI16) xi16_out[o] = (_Float16)(ai + bi);
            else      xi32_out[o] = ai + bi;
        }
    }
}

// ---------------------------------------------------------------------------
// Pass 2: recurrence. One wave per chain, lane j = hidden unit j. LDS reads
// interleaved with dots (fine-grained lgkmcnt), 4 accumulators per gate,
// depth-2 prefetch of the gate streams. Single-wave workgroup: barriers
// reduce to lgkmcnt waits.
// ---------------------------------------------------------------------------
template <int XI16>
__global__ __launch_bounds__(64, 1)
void gru_rec(const _Float16* __restrict__ xu_pre, const _Float16* __restrict__ xr_pre,
             const _Float16* __restrict__ xi16_pre,
             const float* __restrict__ W_input, const float* __restrict__ W_update,
             const float* __restrict__ W_reset,
             float* __restrict__ out)
{
    const int b = blockIdx.x;
    const int j = threadIdx.x;

    __shared__ __align__(16) _Float16 hh[DIM_H];
    __shared__ __align__(16) _Float16 ss[DIM_H];

    h2_t wu[32], wr[32], wi[32];
#pragma unroll
    for (int m = 0; m < 32; ++m) {
        const int k = DIM_IN + 2 * m;
        h2_t a, c, d;
        a[0] = (_Float16)W_update[(k    ) * DIM_H + j];
        a[1] = (_Float16)W_update[(k + 1) * DIM_H + j];
        c[0] = (_Float16)W_reset [(k    ) * DIM_H + j];
        c[1] = (_Float16)W_reset [(k + 1) * DIM_H + j];
        d[0] = (_Float16)W_input [(k    ) * DIM_H + j];
        d[1] = (_Float16)W_input [(k + 1) * DIM_H + j];
        wu[m] = a; wr[m] = c; wi[m] = d;
    }

    hh[j] = (_Float16)0.f;
    float hprev = 0.f;

    const size_t base = (size_t)b * SEQ_LEN * DIM_H + j;
    float xu0 = (float)xu_pre[base];
    float xr0 = (float)xr_pre[base];
    float xi0 = XI16 ? (float)xi16_pre[base] : out[base];
    float xu1 = (float)xu_pre[base + DIM_H];
    float xr1 = (float)xr_pre[base + DIM_H];
    float xi1 = XI16 ? (float)xi16_pre[base + DIM_H] : out[base + DIM_H];
    __syncthreads();

    for (int t = 0; t < SEQ_LEN; ++t) {
        // depth-2 prefetch
        const int tp = (t + 2 < SEQ_LEN) ? (t + 2) : (SEQ_LEN - 1);
        const size_t op = base + (size_t)tp * DIM_H;
        const float xu2 = (float)xu_pre[op];
        const float xr2 = (float)xr_pre[op];
        const float xi2 = XI16 ? (float)xi16_pre[op] : out[op];

        // z,r gates: LDS broadcast reads interleaved with dots, 4 accs/gate
        const H8* hp = (const H8*)hh;
        float az0=0,az1=0,az2=0,az3=0, ar0=0,ar1=0,ar2=0,ar3=0;
#pragma unroll
        for (int q = 0; q < 8; ++q) {
            H8 hx; hx.v = hp[q].v;
            az0 = dot2(hx.p[0], wu[4*q+0], az0);
            ar0 = dot2(hx.p[0], wr[4*q+0], ar0);
            az1 = dot2(hx.p[1], wu[4*q+1], az1);
            ar1 = dot2(hx.p[1], wr[4*q+1], ar1);
            az2 = dot2(hx.p[2], wu[4*q+2], az2);
            ar2 = dot2(hx.p[2], wr[4*q+2], ar2);
            az3 = dot2(hx.p[3], wu[4*q+3], az3);
            ar3 = dot2(hx.p[3], wr[4*q+3], ar3);
        }
        const float z = sigmoid_(xu0 + ((az0 + az1) + (az2 + az3)));
        const float r = sigmoid_(xr0 + ((ar0 + ar1) + (ar2 + ar3)));

        ss[j] = (_Float16)(hprev * r);
        __syncthreads();

        const H8* sp = (const H8*)ss;
        float ax0=0,ax1=0,ax2=0,ax3=0;
#pragma unroll
        for (int q = 0; q < 8; ++q) {
            H8 sx; sx.v = sp[q].v;
            ax0 = dot2(sx.p[0], wi[4*q+0], ax0);
            ax1 = dot2(sx.p[1], wi[4*q+1], ax1);
            ax2 = dot2(sx.p[2], wi[4*q+2], ax2);
            ax3 = dot2(sx.p[3], wi[4*q+3], ax3);
        }
        const float th = tanh_(xi0 + ((ax0 + ax1) + (ax2 + ax3)));
        const float hn = (1.f - z) * hprev + z * th;

        out[base + (size_t)t * DIM_H] = hn;
        hh[j] = (_Float16)hn;
        hprev = hn;
        xu0 = xu1; xr0 = xr1; xi0 = xi1;
        xu1 = xu2; xr1 = xr2; xi1 = xi2;
        __syncthreads();
    }
}

extern "C" void kernel_launch(void* const* d_in, const int* in_sizes, int n_in,
                              void* d_out, int out_size, void* d_ws, size_t ws_size,
                              hipStream_t stream) {
    const float* inputs   = (const float*)d_in[0];
    const float* W_input  = (const float*)d_in[1];
    const float* b_input  = (const float*)d_in[2];
    const float* W_update = (const float*)d_in[3];
    const float* b_update = (const float*)d_in[4];
    const float* W_reset  = (const float*)d_in[5];
    const float* b_reset  = (const float*)d_in[6];
    float* out = (float*)d_out;

    const int    batch = in_sizes[0] / (SEQ_LEN * DIM_IN);
    const size_t rows  = (size_t)batch * SEQ_LEN;

    _Float16* xu_w = (_Float16*)d_ws;
    _Float16* xr_w = xu_w + rows * DIM_H;
    _Float16* xi_w = xr_w + rows * DIM_H;
    const bool xi16 = ws_size >= rows * DIM_H * 2ull * 3ull;   // 50.3 MB at batch=256

    if (xi16) {
        gru_prepass<1><<<(int)(rows / 64), 256, 0, stream>>>(
            inputs, W_input, b_input, W_update, b_update, W_reset, b_reset,
            xu_w, xr_w, xi_w, out);
        gru_rec<1><<<batch, 64, 0, stream>>>(xu_w, xr_w, xi_w,
                                             W_input, W_update, W_reset, out);
    } else {
        gru_prepass<0><<<(int)(rows / 64), 256, 0, stream>>>(
            inputs, W_input, b_input, W_update, b_update, W_reset, b_reset,
            xu_w, xr_w, xi_w, out);
        gru_rec<0><<<batch, 64, 0, stream>>>(xu_w, xr_w, xi_w,
                                             W_input, W_update, W_reset, out);
    }
}

// Round 4
// 485.211 us; speedup vs baseline: 1.3986x; 1.2000x over previous
//
#include <hip/hip_runtime.h>

#define DIM_IN 256
#define DIM_H 64
#define SEQ_LEN 512

typedef _Float16 h2_t  __attribute__((ext_vector_type(2)));
typedef _Float16 h8_t  __attribute__((ext_vector_type(8)));
typedef float    f32x4 __attribute__((ext_vector_type(4)));
union H8 { h8_t v; h2_t p[4]; };

__device__ inline float dot2(h2_t a, h2_t b, float c) {
#if __has_builtin(__builtin_amdgcn_fdot2)
    return __builtin_amdgcn_fdot2(a, b, c, false);
#else
    return c + (float)a[0] * (float)b[0] + (float)a[1] * (float)b[1];
#endif
}
__device__ inline float sigmoid_(float x) { return __fdividef(1.f, 1.f + __expf(-x)); }
__device__ inline float tanh_(float x)    { return 1.f - 2.f * __fdividef(1.f, 1.f + __expf(2.f * x)); }

// Intra-wave LDS ordering WITHOUT s_barrier: waits LDS ops only, leaves the
// global (vmcnt) prefetch stream in flight. "memory" clobber pins ordering.
#define LDS_FENCE() __asm__ volatile("s_waitcnt lgkmcnt(0)" ::: "memory")

// ---------------------------------------------------------------------------
// Pass 1 (MFMA): x-projections for all rows. Grid = rows/64 blocks of 256.
// Wave w owns col tile w*16..w*16+15 for all 3 gates; W B-fragments in
// registers (8 ktiles x 3 mats x 4 VGPRs = 96), X tile staged fp16 in LDS.
// 16x16x32 f16 MFMA, fp32 accumulate (same precision as the dot2 path).
// Output: packed (xu,xr) half2-as-uint + xi (fp16 in ws, or fp32 in out).
// ---------------------------------------------------------------------------
template <int XI16>
__global__ __launch_bounds__(256, 1)
void gru_prepass_mfma(const float* __restrict__ X,
                      const float* __restrict__ W_input,  const float* __restrict__ b_input,
                      const float* __restrict__ W_update, const float* __restrict__ b_update,
                      const float* __restrict__ W_reset,  const float* __restrict__ b_reset,
                      unsigned* __restrict__ xur_out,
                      _Float16* __restrict__ xi16_out, float* __restrict__ xi32_out)
{
    const int tid  = threadIdx.x;
    const int lane = tid & 63;
    const int wv   = tid >> 6;       // wave id -> col tile
    const int q    = lane >> 4;      // quad
    const int m16  = lane & 15;

    constexpr int LDK = DIM_IN + 8;  // 264 fp16 = 528 B row stride (16B-aligned, ~2-way banks)
    __shared__ _Float16 xs[64 * LDK];

    // B-fragments: B[k][n], n = lane&15 (col), k = q*8 + jj within ktile
    const int c = wv * 16 + m16;
    h8_t bu[8], brf[8], bif[8];
#pragma unroll
    for (int kt = 0; kt < 8; ++kt) {
        h8_t u, r, i;
#pragma unroll
        for (int jj = 0; jj < 8; ++jj) {
            const int k = kt * 32 + q * 8 + jj;
            u[jj] = (_Float16)W_update[k * DIM_H + c];
            r[jj] = (_Float16)W_reset [k * DIM_H + c];
            i[jj] = (_Float16)W_input [k * DIM_H + c];
        }
        bu[kt] = u; brf[kt] = r; bif[kt] = i;
    }
    const float bzc = b_update[c], brc = b_reset[c], bic = b_input[c];

    // stage 64 rows of X (fp32 -> fp16), coalesced float4 loads
    const float4* xblk = (const float4*)(X + (size_t)blockIdx.x * 64 * DIM_IN);
#pragma unroll
    for (int i = 0; i < 16; ++i) {
        const int f   = tid + 256 * i;
        const int row = f >> 6;
        const int kq  = f & 63;
        const float4 v = xblk[f];
        h2_t a, b;
        a[0] = (_Float16)v.x; a[1] = (_Float16)v.y;
        b[0] = (_Float16)v.z; b[1] = (_Float16)v.w;
        _Float16* dst = &xs[row * LDK + kq * 4];
        *(h2_t*)dst = a; *(h2_t*)(dst + 2) = b;
    }
    __syncthreads();

    const size_t orow0 = (size_t)blockIdx.x * 64;
#pragma unroll
    for (int rt = 0; rt < 4; ++rt) {
        const int r0 = rt * 16;
        f32x4 au = {0.f,0.f,0.f,0.f}, ar = {0.f,0.f,0.f,0.f}, ai = {0.f,0.f,0.f,0.f};
#pragma unroll
        for (int kt = 0; kt < 8; ++kt) {
            // A[m = lane&15][k = q*8 + jj] — 8 contiguous fp16 = one b128
            const h8_t a = *(const h8_t*)&xs[(r0 + m16) * LDK + kt * 32 + q * 8];
            au = __builtin_amdgcn_mfma_f32_16x16x32_f16(a, bu[kt],  au, 0, 0, 0);
            ar = __builtin_amdgcn_mfma_f32_16x16x32_f16(a, brf[kt], ar, 0, 0, 0);
            ai = __builtin_amdgcn_mfma_f32_16x16x32_f16(a, bif[kt], ai, 0, 0, 0);
        }
        // C/D: col = lane&15, row = q*4 + reg (verified mapping)
#pragma unroll
        for (int i = 0; i < 4; ++i) {
            const size_t grow = orow0 + r0 + q * 4 + i;
            h2_t pk;
            pk[0] = (_Float16)(au[i] + bzc);
            pk[1] = (_Float16)(ar[i] + brc);
            xur_out[grow * DIM_H + c] = __builtin_bit_cast(unsigned, pk);
            const float xiv = ai[i] + bic;
            if (XI16) xi16_out[grow * DIM_H + c] = (_Float16)xiv;
            else      xi32_out[grow * DIM_H + c] = xiv;
        }
    }
}

// ---------------------------------------------------------------------------
// Pass 2: recurrence. One wave per chain; NO s_barrier anywhere in the loop
// (a barrier would drain vmcnt and kill the gate-stream prefetch). LDS
// ordering via lgkmcnt-only fences. Depth-8 ring prefetch of packed gates;
// h staged to an LDS history buffer, flushed to global every 32 steps so
// stores stay out of the steady vm stream.
// ---------------------------------------------------------------------------
template <int XI16>
__global__ __launch_bounds__(64, 1)
void gru_rec(const unsigned* __restrict__ xur, const _Float16* __restrict__ xi16,
             const float* __restrict__ W_input, const float* __restrict__ W_update,
             const float* __restrict__ W_reset,
             float* __restrict__ out)
{
    const int b = blockIdx.x;
    const int j = threadIdx.x;

    __shared__ __align__(16) _Float16 hh[DIM_H];
    __shared__ __align__(16) _Float16 ss[DIM_H];
    __shared__ float hist[32][DIM_H];

    h2_t wu[32], wr[32], wi[32];
#pragma unroll
    for (int m = 0; m < 32; ++m) {
        const int k = DIM_IN + 2 * m;
        h2_t a, cc, d;
        a[0]  = (_Float16)W_update[(k    ) * DIM_H + j];
        a[1]  = (_Float16)W_update[(k + 1) * DIM_H + j];
        cc[0] = (_Float16)W_reset [(k    ) * DIM_H + j];
        cc[1] = (_Float16)W_reset [(k + 1) * DIM_H + j];
        d[0]  = (_Float16)W_input [(k    ) * DIM_H + j];
        d[1]  = (_Float16)W_input [(k + 1) * DIM_H + j];
        wu[m] = a; wr[m] = cc; wi[m] = d;
    }

    hh[j] = (_Float16)0.f;
    float hprev = 0.f;

    const size_t base = (size_t)b * SEQ_LEN * DIM_H + j;
    unsigned ru[8];
    float    rxi[8];
#pragma unroll
    for (int d = 0; d < 8; ++d) {
        const size_t o = base + (size_t)d * DIM_H;
        ru[d]  = xur[o];
        rxi[d] = XI16 ? (float)xi16[o] : out[o];
    }
    LDS_FENCE();

    for (int tb = 0; tb < SEQ_LEN / 32; ++tb) {
#pragma unroll
        for (int u = 0; u < 32; ++u) {
            const int t  = tb * 32 + u;
            const int sl = t & 7;
            // consume ring slot (loaded 8 steps ago), then refill for t+8
            const h2_t pr = __builtin_bit_cast(h2_t, ru[sl]);
            const float xu = (float)pr[0];
            const float xr = (float)pr[1];
            const float xi = rxi[sl];
            const int tp = (t + 8 < SEQ_LEN) ? t + 8 : SEQ_LEN - 1;
            const size_t op = base + (size_t)tp * DIM_H;
            ru[sl]  = xur[op];
            rxi[sl] = XI16 ? (float)xi16[op] : out[op];

            // z/r gates: broadcast-read h from LDS, dual 4-acc dot chains
            const H8* hp = (const H8*)hh;
            float az0=0,az1=0,az2=0,az3=0, ar0=0,ar1=0,ar2=0,ar3=0;
#pragma unroll
            for (int qq = 0; qq < 8; ++qq) {
                H8 hx; hx.v = hp[qq].v;
                az0 = dot2(hx.p[0], wu[4*qq+0], az0);
                ar0 = dot2(hx.p[0], wr[4*qq+0], ar0);
                az1 = dot2(hx.p[1], wu[4*qq+1], az1);
                ar1 = dot2(hx.p[1], wr[4*qq+1], ar1);
                az2 = dot2(hx.p[2], wu[4*qq+2], az2);
                ar2 = dot2(hx.p[2], wr[4*qq+2], ar2);
                az3 = dot2(hx.p[3], wu[4*qq+3], az3);
                ar3 = dot2(hx.p[3], wr[4*qq+3], ar3);
            }
            const float z = sigmoid_(xu + ((az0 + az1) + (az2 + az3)));
            const float r = sigmoid_(xr + ((ar0 + ar1) + (ar2 + ar3)));

            ss[j] = (_Float16)(hprev * r);
            LDS_FENCE();

            const H8* sp = (const H8*)ss;
            float ax0=0,ax1=0,ax2=0,ax3=0;
#pragma unroll
            for (int qq = 0; qq < 8; ++qq) {
                H8 sx; sx.v = sp[qq].v;
                ax0 = dot2(sx.p[0], wi[4*qq+0], ax0);
                ax1 = dot2(sx.p[1], wi[4*qq+1], ax1);
                ax2 = dot2(sx.p[2], wi[4*qq+2], ax2);
                ax3 = dot2(sx.p[3], wi[4*qq+3], ax3);
            }
            const float th = tanh_(xi + ((ax0 + ax1) + (ax2 + ax3)));
            const float hn = (1.f - z) * hprev + z * th;

            hist[u][j] = hn;          // batched output staging
            hh[j] = (_Float16)hn;
            LDS_FENCE();
            hprev = hn;
        }
        // flush 32 steps of h to global (coalesced dword stores)
        float* ob = out + (size_t)b * SEQ_LEN * DIM_H + (size_t)tb * 32 * DIM_H + j;
#pragma unroll
        for (int u = 0; u < 32; ++u)
            ob[u * DIM_H] = hist[u][j];
    }
}

extern "C" void kernel_launch(void* const* d_in, const int* in_sizes, int n_in,
                              void* d_out, int out_size, void* d_ws, size_t ws_size,
                              hipStream_t stream) {
    const float* inputs   = (const float*)d_in[0];
    const float* W_input  = (const float*)d_in[1];
    const float* b_input  = (const float*)d_in[2];
    const float* W_update = (const float*)d_in[3];
    const float* b_update = (const float*)d_in[4];
    const float* W_reset  = (const float*)d_in[5];
    const float* b_reset  = (const float*)d_in[6];
    float* out = (float*)d_out;

    const int    batch = in_sizes[0] / (SEQ_LEN * DIM_IN);
    const size_t rows  = (size_t)batch * SEQ_LEN;

    unsigned* xur_w = (unsigned*)d_ws;                       // rows*64*4 B = 33.6 MB
    _Float16* xi_w  = (_Float16*)(xur_w + rows * DIM_H);     // rows*64*2 B = 16.8 MB
    const bool xi16 = ws_size >= rows * DIM_H * 6ull;        // 50.3 MB (proven available in R3)

    if (xi16) {
        gru_prepass_mfma<1><<<(int)(rows / 64), 256, 0, stream>>>(
            inputs, W_input, b_input, W_update, b_update, W_reset, b_reset,
            xur_w, xi_w, out);
        gru_rec<1><<<batch, 64, 0, stream>>>(xur_w, xi_w,
                                             W_input, W_update, W_reset, out);
    } else {
        gru_prepass_mfma<0><<<(int)(rows / 64), 256, 0, stream>>>(
            inputs, W_input, b_input, W_update, b_update, W_reset, b_reset,
            xur_w, xi_w, out);
        gru_rec<0><<<batch, 64, 0, stream>>>(xur_w, xi_w,
                                             W_input, W_update, W_reset, out);
    }
}

// Round 5
// 481.905 us; speedup vs baseline: 1.4082x; 1.0069x over previous
//
#include <hip/hip_runtime.h>

#define DIM_IN 256
#define DIM_H 64
#define SEQ_LEN 512

typedef _Float16 h2_t  __attribute__((ext_vector_type(2)));
typedef _Float16 h8_t  __attribute__((ext_vector_type(8)));
typedef float    f32x4 __attribute__((ext_vector_type(4)));
union H8 { h8_t v; h2_t p[4]; };

// Guaranteed-global (addrspace 1) pointers: loads/stores through these emit
// global_load_*/global_store_* (vmcnt-only), never flat_* (which would couple
// into lgkmcnt and make the LDS fences drain the gate-stream prefetch).
typedef const __attribute__((address_space(1))) unsigned* gcu32_p;
typedef const __attribute__((address_space(1))) _Float16* gch16_p;
typedef const __attribute__((address_space(1))) float*    gcf32_p;
typedef       __attribute__((address_space(1))) float*    gf32_p;

__device__ inline float dot2(h2_t a, h2_t b, float c) {
#if __has_builtin(__builtin_amdgcn_fdot2)
    return __builtin_amdgcn_fdot2(a, b, c, false);
#else
    return c + (float)a[0] * (float)b[0] + (float)a[1] * (float)b[1];
#endif
}
__device__ inline float sigmoid_(float x) { return __fdividef(1.f, 1.f + __expf(-x)); }
__device__ inline float tanh_(float x)    { return 1.f - 2.f * __fdividef(1.f, 1.f + __expf(2.f * x)); }

// Intra-wave LDS ordering: waits LDS ops only. With AS1 global loads this
// provably leaves the vm prefetch stream in flight.
#define LDS_FENCE() __asm__ volatile("s_waitcnt lgkmcnt(0)" ::: "memory")

// ---------------------------------------------------------------------------
// Pass 1 (MFMA): x-projections for all rows (unchanged from R4 — it works).
// ---------------------------------------------------------------------------
template <int XI16>
__global__ __launch_bounds__(256, 1)
void gru_prepass_mfma(const float* __restrict__ X,
                      const float* __restrict__ W_input,  const float* __restrict__ b_input,
                      const float* __restrict__ W_update, const float* __restrict__ b_update,
                      const float* __restrict__ W_reset,  const float* __restrict__ b_reset,
                      unsigned* __restrict__ xur_out,
                      _Float16* __restrict__ xi16_out, float* __restrict__ xi32_out)
{
    const int tid  = threadIdx.x;
    const int lane = tid & 63;
    const int wv   = tid >> 6;
    const int q    = lane >> 4;
    const int m16  = lane & 15;

    constexpr int LDK = DIM_IN + 8;
    __shared__ _Float16 xs[64 * LDK];

    const int c = wv * 16 + m16;
    h8_t bu[8], brf[8], bif[8];
#pragma unroll
    for (int kt = 0; kt < 8; ++kt) {
        h8_t u, r, i;
#pragma unroll
        for (int jj = 0; jj < 8; ++jj) {
            const int k = kt * 32 + q * 8 + jj;
            u[jj] = (_Float16)W_update[k * DIM_H + c];
            r[jj] = (_Float16)W_reset [k * DIM_H + c];
            i[jj] = (_Float16)W_input [k * DIM_H + c];
        }
        bu[kt] = u; brf[kt] = r; bif[kt] = i;
    }
    const float bzc = b_update[c], brc = b_reset[c], bic = b_input[c];

    const float4* xblk = (const float4*)(X + (size_t)blockIdx.x * 64 * DIM_IN);
#pragma unroll
    for (int i = 0; i < 16; ++i) {
        const int f   = tid + 256 * i;
        const int row = f >> 6;
        const int kq  = f & 63;
        const float4 v = xblk[f];
        h2_t a, b;
        a[0] = (_Float16)v.x; a[1] = (_Float16)v.y;
        b[0] = (_Float16)v.z; b[1] = (_Float16)v.w;
        _Float16* dst = &xs[row * LDK + kq * 4];
        *(h2_t*)dst = a; *(h2_t*)(dst + 2) = b;
    }
    __syncthreads();

    const size_t orow0 = (size_t)blockIdx.x * 64;
#pragma unroll
    for (int rt = 0; rt < 4; ++rt) {
        const int r0 = rt * 16;
        f32x4 au = {0.f,0.f,0.f,0.f}, ar = {0.f,0.f,0.f,0.f}, ai = {0.f,0.f,0.f,0.f};
#pragma unroll
        for (int kt = 0; kt < 8; ++kt) {
            const h8_t a = *(const h8_t*)&xs[(r0 + m16) * LDK + kt * 32 + q * 8];
            au = __builtin_amdgcn_mfma_f32_16x16x32_f16(a, bu[kt],  au, 0, 0, 0);
            ar = __builtin_amdgcn_mfma_f32_16x16x32_f16(a, brf[kt], ar, 0, 0, 0);
            ai = __builtin_amdgcn_mfma_f32_16x16x32_f16(a, bif[kt], ai, 0, 0, 0);
        }
#pragma unroll
        for (int i = 0; i < 4; ++i) {
            const size_t grow = orow0 + r0 + q * 4 + i;
            h2_t pk;
            pk[0] = (_Float16)(au[i] + bzc);
            pk[1] = (_Float16)(ar[i] + brc);
            xur_out[grow * DIM_H + c] = __builtin_bit_cast(unsigned, pk);
            const float xiv = ai[i] + bic;
            if (XI16) xi16_out[grow * DIM_H + c] = (_Float16)xiv;
            else      xi32_out[grow * DIM_H + c] = xiv;
        }
    }
}

// ---------------------------------------------------------------------------
// Pass 2: recurrence. One wave per chain; no s_barrier; lgkm-only fences;
// ALL global traffic through addrspace(1) pointers so the prefetch ring is
// vmcnt-only and never drained by the fences. Unroll 8 (I-cache friendly),
// ring depth 8, direct coalesced output stores.
// ---------------------------------------------------------------------------
template <int XI16>
__global__ __launch_bounds__(64, 1)
void gru_rec(const unsigned* __restrict__ xur, const _Float16* __restrict__ xi16,
             const float* __restrict__ W_input, const float* __restrict__ W_update,
             const float* __restrict__ W_reset,
             float* __restrict__ out)
{
    const int b = blockIdx.x;
    const int j = threadIdx.x;

    __shared__ __align__(16) _Float16 hh[DIM_H];
    __shared__ __align__(16) _Float16 ss[DIM_H];

    h2_t wu[32], wr[32], wi[32];
#pragma unroll
    for (int m = 0; m < 32; ++m) {
        const int k = DIM_IN + 2 * m;
        h2_t a, cc, d;
        a[0]  = (_Float16)W_update[(k    ) * DIM_H + j];
        a[1]  = (_Float16)W_update[(k + 1) * DIM_H + j];
        cc[0] = (_Float16)W_reset [(k    ) * DIM_H + j];
        cc[1] = (_Float16)W_reset [(k + 1) * DIM_H + j];
        d[0]  = (_Float16)W_input [(k    ) * DIM_H + j];
        d[1]  = (_Float16)W_input [(k + 1) * DIM_H + j];
        wu[m] = a; wr[m] = cc; wi[m] = d;
    }

    hh[j] = (_Float16)0.f;
    float hprev = 0.f;

    const size_t base = (size_t)b * SEQ_LEN * DIM_H + j;
    gcu32_p xg  = (gcu32_p)(xur + base);
    gch16_p ig  = (gch16_p)(xi16 + base);
    gcf32_p xog = (gcf32_p)(out + base);   // xi source when XI16 == 0
    gf32_p  og  = (gf32_p)(out + base);

    unsigned ru[8];
    float    rxi[8];
#pragma unroll
    for (int d = 0; d < 8; ++d) {
        ru[d]  = xg[(size_t)d * DIM_H];
        rxi[d] = XI16 ? (float)ig[(size_t)d * DIM_H] : xog[(size_t)d * DIM_H];
    }
    LDS_FENCE();

    for (int tb = 0; tb < SEQ_LEN / 8; ++tb) {
#pragma unroll
        for (int u = 0; u < 8; ++u) {
            const int t = tb * 8 + u;
            // consume ring slot (loaded 8 steps ago), then refill for t+8
            const h2_t pr = __builtin_bit_cast(h2_t, ru[u]);
            const float xu = (float)pr[0];
            const float xr = (float)pr[1];
            const float xi = rxi[u];
            const int tp = (t + 8 < SEQ_LEN) ? t + 8 : SEQ_LEN - 1;
            ru[u]  = xg[(size_t)tp * DIM_H];
            rxi[u] = XI16 ? (float)ig[(size_t)tp * DIM_H] : xog[(size_t)tp * DIM_H];

            // z/r gates: broadcast-read h from LDS, dual 4-acc dot chains
            const H8* hp = (const H8*)hh;
            float az0=0,az1=0,az2=0,az3=0, ar0=0,ar1=0,ar2=0,ar3=0;
#pragma unroll
            for (int qq = 0; qq < 8; ++qq) {
                H8 hx; hx.v = hp[qq].v;
                az0 = dot2(hx.p[0], wu[4*qq+0], az0);
                ar0 = dot2(hx.p[0], wr[4*qq+0], ar0);
                az1 = dot2(hx.p[1], wu[4*qq+1], az1);
                ar1 = dot2(hx.p[1], wr[4*qq+1], ar1);
                az2 = dot2(hx.p[2], wu[4*qq+2], az2);
                ar2 = dot2(hx.p[2], wr[4*qq+2], ar2);
                az3 = dot2(hx.p[3], wu[4*qq+3], az3);
                ar3 = dot2(hx.p[3], wr[4*qq+3], ar3);
            }
            const float z = sigmoid_(xu + ((az0 + az1) + (az2 + az3)));
            const float r = sigmoid_(xr + ((ar0 + ar1) + (ar2 + ar3)));

            ss[j] = (_Float16)(hprev * r);
            LDS_FENCE();

            const H8* sp = (const H8*)ss;
            float ax0=0,ax1=0,ax2=0,ax3=0;
#pragma unroll
            for (int qq = 0; qq < 8; ++qq) {
                H8 sx; sx.v = sp[qq].v;
                ax0 = dot2(sx.p[0], wi[4*qq+0], ax0);
                ax1 = dot2(sx.p[1], wi[4*qq+1], ax1);
                ax2 = dot2(sx.p[2], wi[4*qq+2], ax2);
                ax3 = dot2(sx.p[3], wi[4*qq+3], ax3);
            }
            const float th = tanh_(xi + ((ax0 + ax1) + (ax2 + ax3)));
            const float hn = (1.f - z) * hprev + z * th;

            og[(size_t)t * DIM_H] = hn;    // vmcnt-only, fire-and-forget
            hh[j] = (_Float16)hn;
            LDS_FENCE();
            hprev = hn;
        }
    }
}

extern "C" void kernel_launch(void* const* d_in, const int* in_sizes, int n_in,
                              void* d_out, int out_size, void* d_ws, size_t ws_size,
                              hipStream_t stream) {
    const float* inputs   = (const float*)d_in[0];
    const float* W_input  = (const float*)d_in[1];
    const float* b_input  = (const float*)d_in[2];
    const float* W_update = (const float*)d_in[3];
    const float* b_update = (const float*)d_in[4];
    const float* W_reset  = (const float*)d_in[5];
    const float* b_reset  = (const float*)d_in[6];
    float* out = (float*)d_out;

    const int    batch = in_sizes[0] / (SEQ_LEN * DIM_IN);
    const size_t rows  = (size_t)batch * SEQ_LEN;

    unsigned* xur_w = (unsigned*)d_ws;                       // rows*64*4 B
    _Float16* xi_w  = (_Float16*)(xur_w + rows * DIM_H);     // rows*64*2 B
    const bool xi16 = ws_size >= rows * DIM_H * 6ull;        // 50.3 MB (proven in R3/R4)

    if (xi16) {
        gru_prepass_mfma<1><<<(int)(rows / 64), 256, 0, stream>>>(
            inputs, W_input, b_input, W_update, b_update, W_reset, b_reset,
            xur_w, xi_w, out);
        gru_rec<1><<<batch, 64, 0, stream>>>(xur_w, xi_w,
                                             W_input, W_update, W_reset, out);
    } else {
        gru_prepass_mfma<0><<<(int)(rows / 64), 256, 0, stream>>>(
            inputs, W_input, b_input, W_update, b_update, W_reset, b_reset,
            xur_w, xi_w, out);
        gru_rec<0><<<batch, 64, 0, stream>>>(xur_w, xi_w,
                                             W_input, W_update, W_reset, out);
    }
}